// Round 3
// baseline (193.813 us; speedup 1.0000x reference)
//
#include <hip/hip_runtime.h>
#include <math.h>

#define KW_ELEMS 294912   // 3*3*128*256
#define LR_GD 0.01

// ws layout (bytes):
//   0   : double sum_w
//   8   : double sum_w2
//   16  : int    Gint[15]   (upper triangle of B B^T counts)
//   80  : double c5[5]      (B w sums)
//   128 : float  alphas[5]  (unused now, kept for layout stability)
//   160 : float  W_eff[294912]
#define WS_GINT_OFF  16
#define WS_C5_OFF    80
#define WS_ALPHA_OFF 128
#define WS_WEFF_OFF  160

// ---------------- K1: sum / sumsq of weights (f64) ----------------
__global__ void k_stats(const float* __restrict__ w, double* __restrict__ wsd) {
    __shared__ double s1[256];
    __shared__ double s2[256];
    int tid = threadIdx.x;
    double a = 0.0, b = 0.0;
    for (int i = blockIdx.x * blockDim.x + tid; i < KW_ELEMS; i += gridDim.x * blockDim.x) {
        double v = (double)w[i];
        a += v; b += v * v;
    }
    s1[tid] = a; s2[tid] = b;
    __syncthreads();
    for (int off = 128; off > 0; off >>= 1) {
        if (tid < off) { s1[tid] += s1[tid + off]; s2[tid] += s2[tid + off]; }
        __syncthreads();
    }
    if (tid == 0) { atomicAdd(&wsd[0], s1[0]); atomicAdd(&wsd[1], s2[0]); }
}

// ---------------- K2: G = B B^T counts (int, exact), c = B w (f64) ----------------
__global__ void k_gc(const float* __restrict__ w, void* __restrict__ wsv) {
    const double* wsd = (const double*)wsv;
    int*    gw = (int*)((char*)wsv + WS_GINT_OFF);
    double* cw = (double*)((char*)wsv + WS_C5_OFF);

    __shared__ int    lg[4][15];
    __shared__ double lc[4][5];

    double mean = wsd[0] / (double)KW_ELEMS;
    double var  = wsd[1] / (double)KW_ELEMS - mean * mean;
    float meanf = (float)mean;
    float sigf  = sqrtf((float)var);
    float sh[5];
    #pragma unroll
    for (int m = 0; m < 5; m++) sh[m] = (-1.0f + 0.5f * (float)m) * sigf;

    int g[15];
    double c[5];
    #pragma unroll
    for (int t = 0; t < 15; t++) g[t] = 0;
    #pragma unroll
    for (int i = 0; i < 5; i++) c[i] = 0.0;

    for (int idx = blockIdx.x * blockDim.x + threadIdx.x; idx < KW_ELEMS;
         idx += gridDim.x * blockDim.x) {
        float wf = w[idx];
        float base = wf - meanf;
        int s[5];
        #pragma unroll
        for (int m = 0; m < 5; m++) {
            float arg = base + sh[m];
            s[m] = (arg > 0.0f) ? 1 : ((arg < 0.0f) ? -1 : 0);
        }
        int t = 0;
        #pragma unroll
        for (int i = 0; i < 5; i++) {
            #pragma unroll
            for (int j = i; j < 5; j++) { g[t] += s[i] * s[j]; t++; }
            c[i] += (double)s[i] * (double)wf;
        }
    }
    #pragma unroll
    for (int t = 0; t < 15; t++) {
        int v = g[t];
        for (int off = 32; off > 0; off >>= 1) v += __shfl_down(v, off, 64);
        g[t] = v;
    }
    #pragma unroll
    for (int i = 0; i < 5; i++) {
        double v = c[i];
        for (int off = 32; off > 0; off >>= 1) v += __shfl_down(v, off, 64);
        c[i] = v;
    }
    int wave = threadIdx.x >> 6;
    if ((threadIdx.x & 63) == 0) {
        #pragma unroll
        for (int t = 0; t < 15; t++) lg[wave][t] = g[t];
        #pragma unroll
        for (int i = 0; i < 5; i++) lc[wave][i] = c[i];
    }
    __syncthreads();
    if (threadIdx.x == 0) {
        #pragma unroll
        for (int t = 0; t < 15; t++) {
            int v = lg[0][t] + lg[1][t] + lg[2][t] + lg[3][t];
            atomicAdd(&gw[t], v);
        }
        #pragma unroll
        for (int i = 0; i < 5; i++) {
            double v = lc[0][i] + lc[1][i] + lc[2][i] + lc[3][i];
            atomicAdd(&cw[i], v);
        }
    }
}

// ---------------- closed-form 500-step GD (device fn, runs on 1 thread) ------
__device__ __forceinline__ void mm5(double* __restrict__ D,
                                    const double* __restrict__ X,
                                    const double* __restrict__ Y) {
    #pragma unroll
    for (int i = 0; i < 5; i++) {
        #pragma unroll
        for (int j = 0; j < 5; j++) {
            double s = 0.0;
            #pragma unroll
            for (int k = 0; k < 5; k++) s += X[i * 5 + k] * Y[k * 5 + j];
            D[i * 5 + j] = s;
        }
    }
}

__device__ void compute_alphas(const int* gw, const double* cw,
                               const float* a0f, float* alph_out) {
    double G[25], C[5];
    {
        int t = 0;
        #pragma unroll
        for (int i = 0; i < 5; i++) {
            #pragma unroll
            for (int j = i; j < 5; j++) {
                double v = (double)gw[t] / (double)KW_ELEMS; t++;
                G[i * 5 + j] = v; G[j * 5 + i] = v;
            }
        }
    }
    #pragma unroll
    for (int i = 0; i < 5; i++) C[i] = cw[i] / (double)KW_ELEMS;

    // Cholesky G = L L^T
    double L[25];
    #pragma unroll
    for (int i = 0; i < 25; i++) L[i] = 0.0;
    #pragma unroll
    for (int i = 0; i < 5; i++) {
        #pragma unroll
        for (int j = 0; j <= i; j++) {
            double s = G[i * 5 + j];
            #pragma unroll
            for (int k = 0; k < j; k++) s -= L[i * 5 + k] * L[j * 5 + k];
            if (i == j) L[i * 5 + j] = sqrt(s);
            else        L[i * 5 + j] = s / L[j * 5 + j];
        }
    }
    double y[5], astar[5];
    #pragma unroll
    for (int i = 0; i < 5; i++) {
        double s = C[i];
        #pragma unroll
        for (int k = 0; k < i; k++) s -= L[i * 5 + k] * y[k];
        y[i] = s / L[i * 5 + i];
    }
    #pragma unroll
    for (int ii = 0; ii < 5; ii++) {
        int i = 4 - ii;
        double s = y[i];
        #pragma unroll
        for (int k = 0; k < 5; k++) if (k > i) s -= L[k * 5 + i] * astar[k];
        astar[i] = s / L[i * 5 + i];
    }
    // A = I - LR*G ;  R = A^500  (square-and-multiply, 500 = 0b111110100)
    double A[25], R[25], T[25];
    #pragma unroll
    for (int i = 0; i < 25; i++) A[i] = ((i % 6) == 0 ? 1.0 : 0.0) - LR_GD * G[i];
    #pragma unroll
    for (int i = 0; i < 25; i++) R[i] = A[i];
    const int bits[8] = {1, 1, 1, 1, 0, 1, 0, 0};
    for (int s = 0; s < 8; s++) {
        mm5(T, R, R);
        if (bits[s]) { mm5(R, T, A); }
        else {
            #pragma unroll
            for (int i = 0; i < 25; i++) R[i] = T[i];
        }
    }
    double d0[5];
    #pragma unroll
    for (int i = 0; i < 5; i++) d0[i] = (double)a0f[i] - astar[i];
    #pragma unroll
    for (int i = 0; i < 5; i++) {
        double s = astar[i];
        #pragma unroll
        for (int j = 0; j < 5; j++) s += R[i * 5 + j] * d0[j];
        alph_out[i] = (float)s;
    }
}

// ---------------- K3: W_eff (alphas computed in-block by thread 0) ------------
__global__ void k_weff(const float* __restrict__ w, const float* __restrict__ a0f,
                       void* __restrict__ wsv) {
    const double* wsd = (const double*)wsv;
    const int*    gw = (const int*)((const char*)wsv + WS_GINT_OFF);
    const double* cw = (const double*)((const char*)wsv + WS_C5_OFF);
    float* weff = (float*)((char*)wsv + WS_WEFF_OFF);

    __shared__ float alph[5];
    if (threadIdx.x == 0) compute_alphas(gw, cw, a0f, alph);
    __syncthreads();

    int idx = blockIdx.x * blockDim.x + threadIdx.x;
    if (idx >= KW_ELEMS) return;
    double mean = wsd[0] / (double)KW_ELEMS;
    double var  = wsd[1] / (double)KW_ELEMS - mean * mean;
    float meanf = (float)mean;
    float sigf  = sqrtf((float)var);
    float base = w[idx] - meanf;
    float acc = 0.0f;
    #pragma unroll
    for (int m = 0; m < 5; m++) {
        float arg = base + (-1.0f + 0.5f * (float)m) * sigf;
        float s = (arg > 0.0f) ? 1.0f : ((arg < 0.0f) ? -1.0f : 0.0f);
        acc += alph[m] * s;
    }
    weff[idx] = acc;
}

// ---------------- K4: fused binarize-x + 3x3 conv --------------------------
// grid 1024 = b(8) x h(32) x pos-half(2) x cout-half(2); 256 threads.
// LDS: 3 rows x 18 positions x 128 cin = 27.6 KB -> 4 blocks/CU resident.
// thread: tid&31 -> cout group (4 couts), tid>>5 -> pos pair (2 positions).
__device__ __forceinline__ float xeff_one(float xv, float s0, float s1, float s2,
                                          float be0, float be1, float be2) {
    float t0 = fminf(fmaxf(xv + s0, 0.0f), 1.0f) - 0.5f;
    float t1 = fminf(fmaxf(xv + s1, 0.0f), 1.0f) - 0.5f;
    float t2 = fminf(fmaxf(xv + s2, 0.0f), 1.0f) - 0.5f;
    float g0 = (t0 > 0.0f) ? 1.0f : ((t0 < 0.0f) ? -1.0f : 0.0f);
    float g1 = (t1 > 0.0f) ? 1.0f : ((t1 < 0.0f) ? -1.0f : 0.0f);
    float g2 = (t2 > 0.0f) ? 1.0f : ((t2 < 0.0f) ? -1.0f : 0.0f);
    return be0 * g0 + be1 * g1 + be2 * g2;
}

__global__ __launch_bounds__(256) void k_conv(
    const float* __restrict__ x, const float* __restrict__ shiftp,
    const float* __restrict__ beta, const void* __restrict__ wsv,
    float* __restrict__ out) {
    const float* weff = (const float*)((const char*)wsv + WS_WEFF_OFF);
    __shared__ float lds[3 * 18 * 128];

    int bid  = blockIdx.x;
    int ch   = bid & 1;          // cout half
    int ph   = (bid >> 1) & 1;   // pos half
    int h    = (bid >> 2) & 31;
    int b    = bid >> 7;
    int tid  = threadIdx.x;
    int p0   = ph << 4;          // 0 or 16

    float s0 = shiftp[0], s1 = shiftp[1], s2 = shiftp[2];
    float be0 = beta[0], be1 = beta[1], be2 = beta[2];

    // stage X_eff: rows h-1..h+1, positions p0-1..p0+16 (18), zero-padded
    for (int i = tid; i < 3 * 18 * 32; i += 256) {
        int c4  = i & 31;
        int pos = (i >> 5) % 18;
        int dh  = (i >> 5) / 18;
        int r  = h - 1 + dh;
        int wp = p0 - 1 + pos;
        float4 v = make_float4(0.0f, 0.0f, 0.0f, 0.0f);
        if (r >= 0 && r < 32 && wp >= 0 && wp < 32) {
            float4 xv = *(const float4*)(&x[(((b * 32 + r) * 32) + wp) * 128 + c4 * 4]);
            v.x = xeff_one(xv.x, s0, s1, s2, be0, be1, be2);
            v.y = xeff_one(xv.y, s0, s1, s2, be0, be1, be2);
            v.z = xeff_one(xv.z, s0, s1, s2, be0, be1, be2);
            v.w = xeff_one(xv.w, s0, s1, s2, be0, be1, be2);
        }
        *(float4*)(&lds[(dh * 18 + pos) * 128 + c4 * 4]) = v;
    }
    __syncthreads();

    int cg = tid & 31;           // cout group
    int pg = tid >> 5;           // pos pair index (0..7)
    int c  = (ch << 7) + cg * 4;
    int lp = pg * 2;             // local output pos (0..15 step 2)

    float acc[2][4];
    #pragma unroll
    for (int p = 0; p < 2; p++)
        #pragma unroll
        for (int j = 0; j < 4; j++) acc[p][j] = 0.0f;

    for (int dh = 0; dh < 3; dh++) {
        for (int dw = 0; dw < 3; dw++) {
            const float* wp4  = weff + (dh * 3 + dw) * (128 * 256) + c;
            const float* xrow = lds + (dh * 18 + lp + dw) * 128;
            #pragma unroll 4
            for (int k4 = 0; k4 < 32; k4++) {
                float4 w0 = *(const float4*)(wp4 + (k4 * 4 + 0) * 256);
                float4 w1 = *(const float4*)(wp4 + (k4 * 4 + 1) * 256);
                float4 w2 = *(const float4*)(wp4 + (k4 * 4 + 2) * 256);
                float4 w3 = *(const float4*)(wp4 + (k4 * 4 + 3) * 256);
                #pragma unroll
                for (int p = 0; p < 2; p++) {
                    float4 xv = *(const float4*)(&xrow[p * 128 + k4 * 4]);
                    acc[p][0] = fmaf(xv.x, w0.x, acc[p][0]);
                    acc[p][1] = fmaf(xv.x, w0.y, acc[p][1]);
                    acc[p][2] = fmaf(xv.x, w0.z, acc[p][2]);
                    acc[p][3] = fmaf(xv.x, w0.w, acc[p][3]);
                    acc[p][0] = fmaf(xv.y, w1.x, acc[p][0]);
                    acc[p][1] = fmaf(xv.y, w1.y, acc[p][1]);
                    acc[p][2] = fmaf(xv.y, w1.z, acc[p][2]);
                    acc[p][3] = fmaf(xv.y, w1.w, acc[p][3]);
                    acc[p][0] = fmaf(xv.z, w2.x, acc[p][0]);
                    acc[p][1] = fmaf(xv.z, w2.y, acc[p][1]);
                    acc[p][2] = fmaf(xv.z, w2.z, acc[p][2]);
                    acc[p][3] = fmaf(xv.z, w2.w, acc[p][3]);
                    acc[p][0] = fmaf(xv.w, w3.x, acc[p][0]);
                    acc[p][1] = fmaf(xv.w, w3.y, acc[p][1]);
                    acc[p][2] = fmaf(xv.w, w3.z, acc[p][2]);
                    acc[p][3] = fmaf(xv.w, w3.w, acc[p][3]);
                }
            }
        }
    }

    #pragma unroll
    for (int p = 0; p < 2; p++) {
        int obase = ((b * 32 + h) * 32 + (p0 + lp + p)) * 256 + c;
        *(float4*)(&out[obase]) = make_float4(acc[p][0], acc[p][1], acc[p][2], acc[p][3]);
    }
}

extern "C" void kernel_launch(void* const* d_in, const int* in_sizes, int n_in,
                              void* d_out, int out_size, void* d_ws, size_t ws_size,
                              hipStream_t stream) {
    const float* x      = (const float*)d_in[0];
    const float* w      = (const float*)d_in[1];
    const float* shiftp = (const float*)d_in[2];
    const float* beta   = (const float*)d_in[3];
    const float* a0     = (const float*)d_in[4];
    float* out = (float*)d_out;

    hipMemsetAsync(d_ws, 0, 160, stream);
    k_stats<<<64, 256, 0, stream>>>(w, (double*)d_ws);
    k_gc<<<64, 256, 0, stream>>>(w, d_ws);
    k_weff<<<(KW_ELEMS + 255) / 256, 256, 0, stream>>>(w, a0, d_ws);
    k_conv<<<1024, 256, 0, stream>>>(x, shiftp, beta, d_ws, out);
}

// Round 4
// 73.936 us; speedup vs baseline: 2.6214x; 2.6214x over previous
//
#include <hip/hip_runtime.h>
#include <math.h>

#define KW_ELEMS 294912   // 3*3*128*256
#define LR_GD 0.01

typedef __attribute__((ext_vector_type(8))) short short8;
typedef __attribute__((ext_vector_type(4))) float f32x4;

// ws layout (bytes):
//   0   : double sum_w
//   8   : double sum_w2
//   16  : int    Gint[15]
//   80  : double c5[5]
//   128 : pad
//   160 : ushort W_packed[9][256][128]   (bf16, [tap][cout][cin])
#define WS_GINT_OFF  16
#define WS_C5_OFF    80
#define WS_WP_OFF    160

__device__ __forceinline__ unsigned short f2bf(float f) {
    union { float f; unsigned int u; } v; v.f = f;
    unsigned int r = v.u + 0x7fffu + ((v.u >> 16) & 1u);   // RNE
    return (unsigned short)(r >> 16);
}

// ---------------- K1: sum / sumsq of weights (f64) ----------------
__global__ void k_stats(const float* __restrict__ w, double* __restrict__ wsd) {
    __shared__ double s1[256];
    __shared__ double s2[256];
    int tid = threadIdx.x;
    double a = 0.0, b = 0.0;
    for (int i = blockIdx.x * blockDim.x + tid; i < KW_ELEMS; i += gridDim.x * blockDim.x) {
        double v = (double)w[i];
        a += v; b += v * v;
    }
    s1[tid] = a; s2[tid] = b;
    __syncthreads();
    for (int off = 128; off > 0; off >>= 1) {
        if (tid < off) { s1[tid] += s1[tid + off]; s2[tid] += s2[tid + off]; }
        __syncthreads();
    }
    if (tid == 0) { atomicAdd(&wsd[0], s1[0]); atomicAdd(&wsd[1], s2[0]); }
}

// ---------------- K2: G = B B^T counts (int, exact), c = B w (f64) -----------
__global__ void k_gc(const float* __restrict__ w, void* __restrict__ wsv) {
    const double* wsd = (const double*)wsv;
    int*    gw = (int*)((char*)wsv + WS_GINT_OFF);
    double* cw = (double*)((char*)wsv + WS_C5_OFF);

    __shared__ int    lg[4][15];
    __shared__ double lc[4][5];

    double mean = wsd[0] / (double)KW_ELEMS;
    double var  = wsd[1] / (double)KW_ELEMS - mean * mean;
    float meanf = (float)mean;
    float sigf  = sqrtf((float)var);
    float sh[5];
    #pragma unroll
    for (int m = 0; m < 5; m++) sh[m] = (-1.0f + 0.5f * (float)m) * sigf;

    int g[15];
    double c[5];
    #pragma unroll
    for (int t = 0; t < 15; t++) g[t] = 0;
    #pragma unroll
    for (int i = 0; i < 5; i++) c[i] = 0.0;

    for (int idx = blockIdx.x * blockDim.x + threadIdx.x; idx < KW_ELEMS;
         idx += gridDim.x * blockDim.x) {
        float wf = w[idx];
        float base = wf - meanf;
        int s[5];
        #pragma unroll
        for (int m = 0; m < 5; m++) {
            float arg = base + sh[m];
            s[m] = (arg > 0.0f) ? 1 : ((arg < 0.0f) ? -1 : 0);
        }
        int t = 0;
        #pragma unroll
        for (int i = 0; i < 5; i++) {
            #pragma unroll
            for (int j = i; j < 5; j++) { g[t] += s[i] * s[j]; t++; }
            c[i] += (double)s[i] * (double)wf;
        }
    }
    #pragma unroll
    for (int t = 0; t < 15; t++) {
        int v = g[t];
        for (int off = 32; off > 0; off >>= 1) v += __shfl_down(v, off, 64);
        g[t] = v;
    }
    #pragma unroll
    for (int i = 0; i < 5; i++) {
        double v = c[i];
        for (int off = 32; off > 0; off >>= 1) v += __shfl_down(v, off, 64);
        c[i] = v;
    }
    int wave = threadIdx.x >> 6;
    if ((threadIdx.x & 63) == 0) {
        #pragma unroll
        for (int t = 0; t < 15; t++) lg[wave][t] = g[t];
        #pragma unroll
        for (int i = 0; i < 5; i++) lc[wave][i] = c[i];
    }
    __syncthreads();
    if (threadIdx.x == 0) {
        #pragma unroll
        for (int t = 0; t < 15; t++) {
            int v = lg[0][t] + lg[1][t] + lg[2][t] + lg[3][t];
            atomicAdd(&gw[t], v);
        }
        #pragma unroll
        for (int i = 0; i < 5; i++) {
            double v = lc[0][i] + lc[1][i] + lc[2][i] + lc[3][i];
            atomicAdd(&cw[i], v);
        }
    }
}

// ---------------- closed-form 500-step GD (1 thread) -------------------------
__device__ __forceinline__ void mm5(double* __restrict__ D,
                                    const double* __restrict__ X,
                                    const double* __restrict__ Y) {
    #pragma unroll
    for (int i = 0; i < 5; i++) {
        #pragma unroll
        for (int j = 0; j < 5; j++) {
            double s = 0.0;
            #pragma unroll
            for (int k = 0; k < 5; k++) s += X[i * 5 + k] * Y[k * 5 + j];
            D[i * 5 + j] = s;
        }
    }
}

__device__ void compute_alphas(const int* gw, const double* cw,
                               const float* a0f, float* alph_out) {
    double G[25], C[5];
    {
        int t = 0;
        #pragma unroll
        for (int i = 0; i < 5; i++) {
            #pragma unroll
            for (int j = i; j < 5; j++) {
                double v = (double)gw[t] / (double)KW_ELEMS; t++;
                G[i * 5 + j] = v; G[j * 5 + i] = v;
            }
        }
    }
    #pragma unroll
    for (int i = 0; i < 5; i++) C[i] = cw[i] / (double)KW_ELEMS;

    double L[25];
    #pragma unroll
    for (int i = 0; i < 25; i++) L[i] = 0.0;
    #pragma unroll
    for (int i = 0; i < 5; i++) {
        #pragma unroll
        for (int j = 0; j <= i; j++) {
            double s = G[i * 5 + j];
            #pragma unroll
            for (int k = 0; k < j; k++) s -= L[i * 5 + k] * L[j * 5 + k];
            if (i == j) L[i * 5 + j] = sqrt(s);
            else        L[i * 5 + j] = s / L[j * 5 + j];
        }
    }
    double y[5], astar[5];
    #pragma unroll
    for (int i = 0; i < 5; i++) {
        double s = C[i];
        #pragma unroll
        for (int k = 0; k < i; k++) s -= L[i * 5 + k] * y[k];
        y[i] = s / L[i * 5 + i];
    }
    #pragma unroll
    for (int ii = 0; ii < 5; ii++) {
        int i = 4 - ii;
        double s = y[i];
        #pragma unroll
        for (int k = 0; k < 5; k++) if (k > i) s -= L[k * 5 + i] * astar[k];
        astar[i] = s / L[i * 5 + i];
    }
    double A[25], R[25], T[25];
    #pragma unroll
    for (int i = 0; i < 25; i++) A[i] = ((i % 6) == 0 ? 1.0 : 0.0) - LR_GD * G[i];
    #pragma unroll
    for (int i = 0; i < 25; i++) R[i] = A[i];
    const int bits[8] = {1, 1, 1, 1, 0, 1, 0, 0};   // 500 square-and-multiply
    for (int s = 0; s < 8; s++) {
        mm5(T, R, R);
        if (bits[s]) { mm5(R, T, A); }
        else {
            #pragma unroll
            for (int i = 0; i < 25; i++) R[i] = T[i];
        }
    }
    double d0[5];
    #pragma unroll
    for (int i = 0; i < 5; i++) d0[i] = (double)a0f[i] - astar[i];
    #pragma unroll
    for (int i = 0; i < 5; i++) {
        double s = astar[i];
        #pragma unroll
        for (int j = 0; j < 5; j++) s += R[i * 5 + j] * d0[j];
        alph_out[i] = (float)s;
    }
}

// ---------------- K3: W_packed[tap][cout][cin] bf16 (transposed in LDS) ------
// grid = 9 taps x 4 cin-blocks of 32.
__global__ __launch_bounds__(256) void k_weff(const float* __restrict__ w,
                                              const float* __restrict__ a0f,
                                              void* __restrict__ wsv) {
    const double* wsd = (const double*)wsv;
    const int*    gw = (const int*)((const char*)wsv + WS_GINT_OFF);
    const double* cw = (const double*)((const char*)wsv + WS_C5_OFF);
    unsigned short* wp = (unsigned short*)((char*)wsv + WS_WP_OFF);

    __shared__ float alph[5];
    __shared__ float tile[32 * 256];   // [ci][cout]
    if (threadIdx.x == 0) compute_alphas(gw, cw, a0f, alph);
    __syncthreads();

    int tap  = blockIdx.x >> 2;
    int cin0 = (blockIdx.x & 3) * 32;
    int tid  = threadIdx.x;

    double mean = wsd[0] / (double)KW_ELEMS;
    double var  = wsd[1] / (double)KW_ELEMS - mean * mean;
    float meanf = (float)mean;
    float sigf  = sqrtf((float)var);
    float a0 = alph[0], a1 = alph[1], a2 = alph[2], a3 = alph[3], a4 = alph[4];

    // coalesced read of w[tap][cin0..+32][0..256], compute weff, store to LDS
    for (int i = tid; i < 32 * 64; i += 256) {
        int ci = i >> 6;
        int c4 = i & 63;
        float4 v = *(const float4*)(&w[(tap * 128 + cin0 + ci) * 256 + c4 * 4]);
        float r[4] = {v.x, v.y, v.z, v.w};
        #pragma unroll
        for (int j = 0; j < 4; j++) {
            float base = r[j] - meanf;
            float acc = 0.0f;
            float al[5] = {a0, a1, a2, a3, a4};
            #pragma unroll
            for (int m = 0; m < 5; m++) {
                float arg = base + (-1.0f + 0.5f * (float)m) * sigf;
                float s = (arg > 0.0f) ? 1.0f : ((arg < 0.0f) ? -1.0f : 0.0f);
                acc += al[m] * s;
            }
            r[j] = acc;
        }
        *(float4*)(&tile[ci * 256 + c4 * 4]) = make_float4(r[0], r[1], r[2], r[3]);
    }
    __syncthreads();

    // transpose out: thread = cout, write 32 bf16 along cin
    int cout = tid;
    unsigned short ob[32];
    #pragma unroll
    for (int ci = 0; ci < 32; ci++) ob[ci] = f2bf(tile[ci * 256 + cout]);
    unsigned short* dst = wp + (tap * 256 + cout) * 128 + cin0;
    #pragma unroll
    for (int j = 0; j < 4; j++)
        *(short8*)(dst + j * 8) = *(short8*)(&ob[j * 8]);
}

// ---------------- K4: fused binarize-x + 3x3 conv via bf16 MFMA --------------
// grid 512 = b(8) x h(32) x cout-half(2); 256 thr = 4 waves.
// wave w: couts ch*128 + w*32 .. +32, all 32 positions of row h.
// LDS: X_eff bf16 [3 rows][34 pos][128 cin], XOR-swizzled 16B blocks.
__device__ __forceinline__ float xeff_one(float xv, float s0, float s1, float s2,
                                          float be0, float be1, float be2) {
    float t0 = fminf(fmaxf(xv + s0, 0.0f), 1.0f) - 0.5f;
    float t1 = fminf(fmaxf(xv + s1, 0.0f), 1.0f) - 0.5f;
    float t2 = fminf(fmaxf(xv + s2, 0.0f), 1.0f) - 0.5f;
    float g0 = (t0 > 0.0f) ? 1.0f : ((t0 < 0.0f) ? -1.0f : 0.0f);
    float g1 = (t1 > 0.0f) ? 1.0f : ((t1 < 0.0f) ? -1.0f : 0.0f);
    float g2 = (t2 > 0.0f) ? 1.0f : ((t2 < 0.0f) ? -1.0f : 0.0f);
    return be0 * g0 + be1 * g1 + be2 * g2;
}

__global__ __launch_bounds__(256) void k_conv(
    const float* __restrict__ x, const float* __restrict__ shiftp,
    const float* __restrict__ beta, const void* __restrict__ wsv,
    float* __restrict__ out) {
    const unsigned short* wp = (const unsigned short*)((const char*)wsv + WS_WP_OFF);
    __shared__ __align__(16) unsigned short ldsx[3 * 34 * 128];   // 26112 B

    int bid = blockIdx.x;
    int ch  = bid & 1;
    int h   = (bid >> 1) & 31;
    int b   = bid >> 6;
    int tid = threadIdx.x;

    float s0 = shiftp[0], s1 = shiftp[1], s2 = shiftp[2];
    float be0 = beta[0], be1 = beta[1], be2 = beta[2];

    // stage X_eff (bf16) rows h-1..h+1, positions -1..32, swizzled
    for (int i = tid; i < 3 * 34 * 16; i += 256) {
        int cb   = i & 15;            // 8-cin chunk
        int pos  = (i >> 4) % 34;
        int drow = (i >> 4) / 34;
        int r  = h - 1 + drow;
        int wpos = pos - 1;
        unsigned short v[8] = {0, 0, 0, 0, 0, 0, 0, 0};
        if (r >= 0 && r < 32 && wpos >= 0 && wpos < 32) {
            const float* xp = &x[(((b * 32 + r) * 32) + wpos) * 128 + cb * 8];
            float4 x0 = *(const float4*)(xp);
            float4 x1 = *(const float4*)(xp + 4);
            float e[8] = {x0.x, x0.y, x0.z, x0.w, x1.x, x1.y, x1.z, x1.w};
            #pragma unroll
            for (int j = 0; j < 8; j++)
                v[j] = f2bf(xeff_one(e[j], s0, s1, s2, be0, be1, be2));
        }
        int row = drow * 34 + pos;
        int byteoff = row * 256 + ((cb * 16) ^ ((row & 7) << 4));
        *(short8*)((char*)ldsx + byteoff) = *(short8*)v;
    }
    __syncthreads();

    int lane = tid & 63;
    int wave = tid >> 6;
    int l15  = lane & 15;
    int kg   = lane >> 4;            // 0..3
    int coutbase = (ch << 7) + wave * 32;

    f32x4 acc[2][2];
    #pragma unroll
    for (int mt = 0; mt < 2; mt++)
        #pragma unroll
        for (int nt = 0; nt < 2; nt++) acc[mt][nt] = (f32x4){0.f, 0.f, 0.f, 0.f};

    for (int dh = 0; dh < 3; dh++) {
        for (int dw = 0; dw < 3; dw++) {
            int tap = dh * 3 + dw;
            int r0 = dh * 34 + l15 + dw;       // input row idx for mtile 0
            int r1 = r0 + 16;                  // mtile 1
            const unsigned short* wb =
                wp + ((tap * 256 + coutbase + l15) * 128 + kg * 8);
            #pragma unroll
            for (int c0 = 0; c0 < 128; c0 += 32) {
                int cbyte = c0 * 2 + kg * 16;
                short8 a0f8 = *(const short8*)((const char*)ldsx +
                               (r0 * 256 + (cbyte ^ ((r0 & 7) << 4))));
                short8 a1f8 = *(const short8*)((const char*)ldsx +
                               (r1 * 256 + (cbyte ^ ((r1 & 7) << 4))));
                short8 b0f8 = *(const short8*)(wb + c0);
                short8 b1f8 = *(const short8*)(wb + 16 * 128 + c0);
                acc[0][0] = __builtin_amdgcn_mfma_f32_16x16x32_bf16(a0f8, b0f8, acc[0][0], 0, 0, 0);
                acc[0][1] = __builtin_amdgcn_mfma_f32_16x16x32_bf16(a0f8, b1f8, acc[0][1], 0, 0, 0);
                acc[1][0] = __builtin_amdgcn_mfma_f32_16x16x32_bf16(a1f8, b0f8, acc[1][0], 0, 0, 0);
                acc[1][1] = __builtin_amdgcn_mfma_f32_16x16x32_bf16(a1f8, b1f8, acc[1][1], 0, 0, 0);
            }
        }
    }

    // write: D col = lane&15 (cout), row = kg*4 + reg (pos within 16-tile)
    #pragma unroll
    for (int mt = 0; mt < 2; mt++) {
        #pragma unroll
        for (int nt = 0; nt < 2; nt++) {
            int col = coutbase + nt * 16 + l15;
            #pragma unroll
            for (int reg = 0; reg < 4; reg++) {
                int row = mt * 16 + kg * 4 + reg;
                out[(((b * 32 + h) * 32) + row) * 256 + col] = acc[mt][nt][reg];
            }
        }
    }
}

extern "C" void kernel_launch(void* const* d_in, const int* in_sizes, int n_in,
                              void* d_out, int out_size, void* d_ws, size_t ws_size,
                              hipStream_t stream) {
    const float* x      = (const float*)d_in[0];
    const float* w      = (const float*)d_in[1];
    const float* shiftp = (const float*)d_in[2];
    const float* beta   = (const float*)d_in[3];
    const float* a0     = (const float*)d_in[4];
    float* out = (float*)d_out;

    hipMemsetAsync(d_ws, 0, 160, stream);
    k_stats<<<64, 256, 0, stream>>>(w, (double*)d_ws);
    k_gc<<<64, 256, 0, stream>>>(w, d_ws);
    k_weff<<<36, 256, 0, stream>>>(w, a0, d_ws);
    k_conv<<<512, 256, 0, stream>>>(x, shiftp, beta, d_ws, out);
}